// Round 17
// baseline (2499.810 us; speedup 1.0000x reference)
//
#include <hip/hip_runtime.h>
#include <hip/hip_bf16.h>

typedef __bf16  bf16_8 __attribute__((ext_vector_type(8)));
typedef short   s16_8  __attribute__((ext_vector_type(8)));
typedef float   f32_4  __attribute__((ext_vector_type(4)));

#define T_ 512

// Issue 8 global_load_dwordx4 (stride 1024B) from b0 (i=0..3), b0+4096 (4..7).
#define LD8(d0,d1,d2,d3,d4,d5,d6,d7, BASE)                                  \
  { unsigned long long _b0 = (BASE), _b1 = (BASE) + 4096ull;                \
    asm volatile(                                                           \
      "global_load_dwordx4 %0, %8, off\n\t"                                 \
      "global_load_dwordx4 %1, %8, off offset:1024\n\t"                     \
      "global_load_dwordx4 %2, %8, off offset:2048\n\t"                     \
      "global_load_dwordx4 %3, %8, off offset:3072\n\t"                     \
      "global_load_dwordx4 %4, %9, off\n\t"                                 \
      "global_load_dwordx4 %5, %9, off offset:1024\n\t"                     \
      "global_load_dwordx4 %6, %9, off offset:2048\n\t"                     \
      "global_load_dwordx4 %7, %9, off offset:3072\n\t"                     \
      : "=&v"(d0),"=&v"(d1),"=&v"(d2),"=&v"(d3),                            \
        "=&v"(d4),"=&v"(d5),"=&v"(d6),"=&v"(d7)                             \
      : "v"(_b0), "v"(_b1)); }

// Coherent 4-load (one mt group, 4 chunks): sc0 sc1 = LLC-direct (r11-proven).
#define LD4C(d0,d1,d2,d3, BASE)                                             \
  { unsigned long long _b0 = (BASE);                                        \
    asm volatile(                                                           \
      "global_load_dwordx4 %0, %4, off sc0 sc1\n\t"                         \
      "global_load_dwordx4 %1, %4, off offset:1024 sc0 sc1\n\t"             \
      "global_load_dwordx4 %2, %4, off offset:2048 sc0 sc1\n\t"             \
      "global_load_dwordx4 %3, %4, off offset:3072 sc0 sc1\n\t"             \
      : "=&v"(d0),"=&v"(d1),"=&v"(d2),"=&v"(d3)                             \
      : "v"(_b0)); }

#define LD32(AF, BASE)                                                      \
  LD8(AF[0][0],AF[0][1],AF[0][2],AF[0][3],AF[0][4],AF[0][5],AF[0][6],AF[0][7], (BASE));          \
  LD8(AF[1][0],AF[1][1],AF[1][2],AF[1][3],AF[1][4],AF[1][5],AF[1][6],AF[1][7], (BASE)+32768ull); \
  LD8(AF[2][0],AF[2][1],AF[2][2],AF[2][3],AF[2][4],AF[2][5],AF[2][6],AF[2][7], (BASE)+65536ull); \
  LD8(AF[3][0],AF[3][1],AF[3][2],AF[3][3],AF[3][4],AF[3][5],AF[3][6],AF[3][7], (BASE)+98304ull);

#define LD16C4(AF, BASE)                                                    \
  LD4C(AF[0][0],AF[0][1],AF[0][2],AF[0][3], (BASE));                        \
  LD4C(AF[1][0],AF[1][1],AF[1][2],AF[1][3], (BASE)+32768ull);               \
  LD4C(AF[2][0],AF[2][1],AF[2][2],AF[2][3], (BASE)+65536ull);               \
  LD4C(AF[3][0],AF[3][1],AF[3][2],AF[3][3], (BASE)+98304ull);

#define VMWAIT_FENCE                                                        \
  asm volatile("s_waitcnt vmcnt(0)" ::: "memory");                          \
  __builtin_amdgcn_sched_barrier(0)

// ---------------- P1: X fp32 [T][B][1024] -> xfrag bf16 [T][4 mt][32 kc][64 lane][8]
__global__ __launch_bounds__(256) void p1_xfrag(const float* __restrict__ X,
                                                bf16_8* __restrict__ xf) {
  size_t n = (size_t)blockIdx.x * 256 + threadIdx.x;   // 4,194,304 total
  int lane = (int)(n & 63);
  int kc   = (int)((n >> 6) & 31);
  int mt   = (int)((n >> 11) & 3);
  int t    = (int)(n >> 13);
  int b  = 16 * mt + (lane & 15);
  int i0 = 32 * kc + (lane >> 4) * 8;
  const float4* ps = (const float4*)(X + ((size_t)t * 64 + b) * 1024 + i0);
  float4 a = ps[0], c = ps[1];
  bf16_8 v;
  v[0]=(__bf16)a.x; v[1]=(__bf16)a.y; v[2]=(__bf16)a.z; v[3]=(__bf16)a.w;
  v[4]=(__bf16)c.x; v[5]=(__bf16)c.y; v[6]=(__bf16)c.z; v[7]=(__bf16)c.w;
  xf[n] = v;
}

// ---------------- P2: Wi,Wh fp32 -> wfrag bf16 [256 cu][64 kc][64 lane][8]
__global__ __launch_bounds__(256) void p2_wfrag(const float* __restrict__ Wi,
                                                const float* __restrict__ Wh,
                                                bf16_8* __restrict__ wf) {
  size_t n = (size_t)blockIdx.x * 256 + threadIdx.x;   // 1,048,576 total
  int lane = (int)(n & 63);
  int kc   = (int)((n >> 6) & 63);
  int cu   = (int)(n >> 12);
  int n16 = lane & 15;
  int g  = n16 >> 2;
  int jj = n16 & 3;
  int col = 4 * cu + jj;
  int k = 32 * kc + (lane >> 4) * 8;
  const float* src = (k < 1024)
      ? (Wi + ((size_t)g * 1024 + col) * 1024 + k)
      : (Wh + ((size_t)g * 1024 + col) * 1024 + (k - 1024));
  const float4* ps = (const float4*)src;
  float4 a = ps[0], c = ps[1];
  bf16_8 v;
  v[0]=(__bf16)a.x; v[1]=(__bf16)a.y; v[2]=(__bf16)a.z; v[3]=(__bf16)a.w;
  v[4]=(__bf16)c.x; v[5]=(__bf16)c.y; v[6]=(__bf16)c.z; v[7]=(__bf16)c.w;
  wf[n] = v;
}

// ---------------- persistent LSTM: 256 blocks x 512 threads, ONE sync/step,
// PUSH-BASED completion: atomicAdd returns old -> the 32nd arriver of a group
// RMWs the root; the 8th group-completion writes the 8 flag copies directly.
// No certifier, no certify-poll, no sleep on the completion path. The only
// polls left are the consumer gates (read-only flag lines, r16-proven).
__global__ __launch_bounds__(512, 2) void lstm_persist(
    const float* __restrict__ bi, const float* __restrict__ bh,
    const s16_8* __restrict__ xfrag, const s16_8* __restrict__ wfrag,
    s16_8* __restrict__ hfrag, float* __restrict__ out,
    unsigned int* __restrict__ ctr)
{
  __shared__ float gx[2][4][64][17];    // x-partials, dbuf           34,816 B
  __shared__ float gh[8][64][17];       // h-partials (8 waves)       34,816 B
  __shared__ float hvals[2][4][64];     // h results, dbuf             2,048 B
  __shared__ unsigned cell_done;        // intra-block arrive counter

  const int tid  = threadIdx.x;
  const int cu   = blockIdx.x;
  const int wv   = tid >> 6;
  const int lane = tid & 63;
  const bool ish = (wv >= 4);

  // resident W B-frags: h-slice (4 chunks) all waves; x-slice x-waves only
  s16_8 whf[4];
#pragma unroll
  for (int i = 0; i < 4; ++i)
    whf[i] = wfrag[((size_t)cu * 64 + 32 + wv * 4 + i) * 64 + lane];
#pragma unroll
  for (int i = 0; i < 4; ++i) asm volatile("" : "+v"(whf[i]));
  s16_8 wxf[8];
  if (!ish) {
#pragma unroll
    for (int i = 0; i < 8; ++i)
      wxf[i] = wfrag[((size_t)cu * 64 + wv * 8 + i) * 64 + lane];
#pragma unroll
    for (int i = 0; i < 8; ++i) asm volatile("" : "+v"(wxf[i]));
  }

  // cell identity (threads 256..511): 4 consecutive lanes = 4 cols of 1 batch
  const int et  = tid - 256;
  const int ejj = et & 3;
  const int eb  = et >> 2;
  const int j   = cu * 4 + ejj;
  float bias4[4] = {0.f, 0.f, 0.f, 0.f};
  if (ish) {
#pragma unroll
    for (int g = 0; g < 4; ++g) bias4[g] = bi[g * 1024 + j] + bh[g * 1024 + j];
  }
  float cst = 0.f, hval = 0.f;

  unsigned int* grp  = ctr + (cu >> 5) * 64;   // 8 group counters, 256 B apart
  unsigned int* root = ctr + 512;              // root counter, own line
  unsigned int* flg  = ctr + 1024 + wv * 64;   // this wave's flag copy

  if (tid == 0) cell_done = 0u;

  // ---- prologue: x-waves compute gx(0)
  if (!ish) {
    s16_8 af[4][8];
    LD32(af, (unsigned long long)(const char*)xfrag
             + (unsigned)(wv * 8192 + lane * 16));
    VMWAIT_FENCE;
    f32_4 acc[4];
#pragma unroll
    for (int mt = 0; mt < 4; ++mt) { f32_4 z = {0.f,0.f,0.f,0.f}; acc[mt] = z; }
#pragma unroll
    for (int i = 0; i < 8; ++i)
#pragma unroll
      for (int mt = 0; mt < 4; ++mt)
        acc[mt] = __builtin_amdgcn_mfma_f32_16x16x32_bf16(af[mt][i], wxf[i], acc[mt], 0, 0, 0);
#pragma unroll
    for (int mt = 0; mt < 4; ++mt)
#pragma unroll
      for (int r = 0; r < 4; ++r)
        gx[0][wv][mt * 16 + (lane >> 4) * 4 + r][lane & 15] = acc[mt][r];
  }
  __syncthreads();

  for (int t = 0; t < T_; ++t) {
    // ---- phase A: self-gate, then all 8 waves h-GEMM h(t-1) (LLC-direct)
    if (t > 0) {
      if (lane == 0) {
        while (__hip_atomic_load(flg, __ATOMIC_RELAXED, __HIP_MEMORY_SCOPE_AGENT)
               < (unsigned)t) {}
      }
      __builtin_amdgcn_sched_barrier(0);   // h loads may not hoist above gate
    }
    {
      s16_8 af[4][4];
      LD16C4(af, (unsigned long long)((const char*)hfrag + (size_t)(t & 1) * 131072)
                 + (unsigned)(wv * 4096 + lane * 16));
      VMWAIT_FENCE;
      f32_4 acc[4];
#pragma unroll
      for (int mt = 0; mt < 4; ++mt) { f32_4 z = {0.f,0.f,0.f,0.f}; acc[mt] = z; }
#pragma unroll
      for (int i = 0; i < 4; ++i)
#pragma unroll
        for (int mt = 0; mt < 4; ++mt)
          acc[mt] = __builtin_amdgcn_mfma_f32_16x16x32_bf16(af[mt][i], whf[i], acc[mt], 0, 0, 0);
#pragma unroll
      for (int mt = 0; mt < 4; ++mt)
#pragma unroll
        for (int r = 0; r < 4; ++r)
          gh[wv][mt * 16 + (lane >> 4) * 4 + r][lane & 15] = acc[mt][r];
    }
    __syncthreads();                       // THE one block barrier per step

    // ---- B-region (no further block syncs)
    if (ish) {
      // cell update
      const int xb = t & 1;
      float g4[4];
#pragma unroll
      for (int g = 0; g < 4; ++g) {
        float s = bias4[g];
        const int row = g * 4 + ejj;
#pragma unroll
        for (int w = 0; w < 4; ++w) s += gx[xb][w][eb][row];
#pragma unroll
        for (int w = 0; w < 8; ++w) s += gh[w][eb][row];
        g4[g] = s;
      }
      float fg = 1.f / (1.f + __expf(-g4[0]));
      float ig = 1.f / (1.f + __expf(-g4[1]));
      float gg = 1.f - 2.f / (__expf(2.f * g4[2]) + 1.f);   // tanh, inf-safe
      float og = 1.f / (1.f + __expf(-g4[3]));
      cst  = fg * cst + ig * gg;
      hval = og * (1.f - 2.f / (__expf(2.f * cst) + 1.f));
      hvals[t & 1][ejj][eb] = hval;

      if (t + 1 < T_) {
        // shfl-pack 4 cols of this batch -> one 8B agent store per 4 lanes
        int base = lane & ~3;
        float p0 = __shfl(hval, base);
        float p1 = __shfl(hval, base + 1);
        float p2 = __shfl(hval, base + 2);
        float p3 = __shfl(hval, base + 3);
        if ((lane & 3) == 0) {
          unsigned long long pk =
              (unsigned long long)__builtin_bit_cast(unsigned short, (__bf16)p0)
            | ((unsigned long long)__builtin_bit_cast(unsigned short, (__bf16)p1) << 16)
            | ((unsigned long long)__builtin_bit_cast(unsigned short, (__bf16)p2) << 32)
            | ((unsigned long long)__builtin_bit_cast(unsigned short, (__bf16)p3) << 48);
          size_t grpi = ((size_t)(((t + 1) & 1) * 4 + (eb >> 4)) * 32 + (cu >> 3)) * 64
                        + (eb & 15) + 16 * ((cu & 7) >> 1);
          unsigned long long* dst =
              (unsigned long long*)((char*)hfrag + grpi * 16 + (cu & 1) * 8);
          __hip_atomic_store(dst, pk, __ATOMIC_RELAXED, __HIP_MEMORY_SCOPE_AGENT);
        }
        asm volatile("s_waitcnt vmcnt(0)" ::: "memory");   // own publish acked
        if (lane == 0)
          __hip_atomic_fetch_add(&cell_done, 1u, __ATOMIC_RELAXED,
                                 __HIP_MEMORY_SCOPE_WORKGROUP);
        if (wv == 4 && lane == 0) {        // single global arrive per CU
          while (__hip_atomic_load(&cell_done, __ATOMIC_RELAXED,
                                   __HIP_MEMORY_SCOPE_WORKGROUP) < 4u * (unsigned)(t + 1)) {}
          // push-based completion cascade: last arriver relays upward
          unsigned old = atomicAdd(grp, 1u);
          if (old == 32u * (unsigned)(t + 1) - 1u) {       // group complete
            unsigned old2 = atomicAdd(root, 1u);
            if (old2 == 8u * (unsigned)(t + 1) - 1u) {     // all groups done
#pragma unroll
              for (int i = 0; i < 8; ++i)
                __hip_atomic_store(ctr + 1024 + i * 64, (unsigned)(t + 1),
                                   __ATOMIC_RELAXED, __HIP_MEMORY_SCOPE_AGENT);
            }
          }
        }
      }
    } else {
      // out(t-1), coalesced float4 (lanes 0-15 per wave, 16 rows each)
      if (t > 0 && lane < 16) {
        const int s = (t - 1) & 1;
        const int row = wv * 16 + lane;
        float4 o4 = make_float4(hvals[s][0][row], hvals[s][1][row],
                                hvals[s][2][row], hvals[s][3][row]);
        *(float4*)(out + ((size_t)(t - 1) * 64 + row) * 1024 + cu * 4) = o4;
      }
      // x-GEMM(t+1) into gx[(t+1)&1] — overlaps cell + completion cascade
      if (t + 1 < T_) {
        s16_8 af[4][8];
        LD32(af, (unsigned long long)((const char*)xfrag + (size_t)(t + 1) * 131072)
                 + (unsigned)(wv * 8192 + lane * 16));
        VMWAIT_FENCE;
        f32_4 acc[4];
#pragma unroll
        for (int mt = 0; mt < 4; ++mt) { f32_4 z = {0.f,0.f,0.f,0.f}; acc[mt] = z; }
#pragma unroll
        for (int i = 0; i < 8; ++i)
#pragma unroll
          for (int mt = 0; mt < 4; ++mt)
            acc[mt] = __builtin_amdgcn_mfma_f32_16x16x32_bf16(af[mt][i], wxf[i], acc[mt], 0, 0, 0);
#pragma unroll
        for (int mt = 0; mt < 4; ++mt)
#pragma unroll
          for (int r = 0; r < 4; ++r)
            gx[(t + 1) & 1][wv][mt * 16 + (lane >> 4) * 4 + r][lane & 15] = acc[mt][r];
      }
    }
  }

  __syncthreads();
  // ---- epilogue: out(511) + h_n, c_n
  if (!ish && lane < 16) {
    const int row = wv * 16 + lane;
    float4 o4 = make_float4(hvals[1][0][row], hvals[1][1][row],
                            hvals[1][2][row], hvals[1][3][row]);
    *(float4*)(out + ((size_t)(T_ - 1) * 64 + row) * 1024 + cu * 4) = o4;
  }
  if (ish) {
    out[(size_t)T_ * 65536 + (size_t)eb * 1024 + j] = hval;
    out[(size_t)T_ * 65536 + 65536 + (size_t)eb * 1024 + j] = cst;
  }
}

extern "C" void kernel_launch(void* const* d_in, const int* in_sizes, int n_in,
                              void* d_out, int out_size, void* d_ws, size_t ws_size,
                              hipStream_t stream) {
  (void)in_sizes; (void)n_in;
  const float* X  = (const float*)d_in[0];
  const float* Wi = (const float*)d_in[1];
  const float* Wh = (const float*)d_in[2];
  const float* bi = (const float*)d_in[3];
  const float* bh = (const float*)d_in[4];
  float* out = (float*)d_out;

  char* ws = (char*)d_ws;
  const size_t W_BYTES = (size_t)256 * 64 * 64 * 8 * 2;     // 16,777,216
  const size_t H_BYTES = (size_t)2 * 4 * 32 * 64 * 8 * 2;   //    262,144
  const size_t C_BYTES = 8192;                              // ctrs + root + flags
  const size_t X_BYTES = (size_t)512 * 4 * 32 * 64 * 8 * 2; // 67,108,864

  bf16_8* wfrag = (bf16_8*)ws;
  bf16_8* hfrag = (bf16_8*)(ws + W_BYTES);
  unsigned int* ctr = (unsigned int*)(ws + W_BYTES + H_BYTES);

  bf16_8* xfrag;
  if (ws_size >= W_BYTES + H_BYTES + C_BYTES + X_BYTES) {
    xfrag = (bf16_8*)(ws + W_BYTES + H_BYTES + C_BYTES);
  } else {
    // place x-frags in the tail of d_out; out rows clobber xfrag[t'] only for
    // t' < 2t-514 < t+1 (already consumed, skew<=1); final outputs cover all.
    size_t out_bytes = (size_t)out_size * 4;
    xfrag = (bf16_8*)((char*)d_out + out_bytes - X_BYTES);
  }

  hipMemsetAsync(hfrag, 0, 131072, stream);   // zero h buffer 0 (t=0 reads it)
  hipMemsetAsync(ctr, 0, C_BYTES, stream);    // reset counters + root + flags

  hipLaunchKernelGGL(p1_xfrag, dim3(16384), dim3(256), 0, stream, X, xfrag);
  hipLaunchKernelGGL(p2_wfrag, dim3(4096), dim3(256), 0, stream, Wi, Wh, wfrag);
  hipLaunchKernelGGL(lstm_persist, dim3(256), dim3(512), 0, stream,
                     bi, bh, (const s16_8*)xfrag, (const s16_8*)wfrag,
                     (s16_8*)hfrag, out, ctr);
}

// Round 18
// 2223.984 us; speedup vs baseline: 1.1240x; 1.1240x over previous
//
#include <hip/hip_runtime.h>
#include <hip/hip_bf16.h>

typedef __bf16  bf16_8 __attribute__((ext_vector_type(8)));
typedef short   s16_8  __attribute__((ext_vector_type(8)));
typedef float   f32_4  __attribute__((ext_vector_type(4)));

#define T_ 512

// Issue 8 global_load_dwordx4 (stride 1024B) from b0 (i=0..3), b0+4096 (4..7).
#define LD8(d0,d1,d2,d3,d4,d5,d6,d7, BASE)                                  \
  { unsigned long long _b0 = (BASE), _b1 = (BASE) + 4096ull;                \
    asm volatile(                                                           \
      "global_load_dwordx4 %0, %8, off\n\t"                                 \
      "global_load_dwordx4 %1, %8, off offset:1024\n\t"                     \
      "global_load_dwordx4 %2, %8, off offset:2048\n\t"                     \
      "global_load_dwordx4 %3, %8, off offset:3072\n\t"                     \
      "global_load_dwordx4 %4, %9, off\n\t"                                 \
      "global_load_dwordx4 %5, %9, off offset:1024\n\t"                     \
      "global_load_dwordx4 %6, %9, off offset:2048\n\t"                     \
      "global_load_dwordx4 %7, %9, off offset:3072\n\t"                     \
      : "=&v"(d0),"=&v"(d1),"=&v"(d2),"=&v"(d3),                            \
        "=&v"(d4),"=&v"(d5),"=&v"(d6),"=&v"(d7)                             \
      : "v"(_b0), "v"(_b1)); }

// Coherent 4-load (one mt group, 4 chunks): sc0 sc1 = LLC-direct (r11-proven).
#define LD4C(d0,d1,d2,d3, BASE)                                             \
  { unsigned long long _b0 = (BASE);                                        \
    asm volatile(                                                           \
      "global_load_dwordx4 %0, %4, off sc0 sc1\n\t"                         \
      "global_load_dwordx4 %1, %4, off offset:1024 sc0 sc1\n\t"             \
      "global_load_dwordx4 %2, %4, off offset:2048 sc0 sc1\n\t"             \
      "global_load_dwordx4 %3, %4, off offset:3072 sc0 sc1\n\t"             \
      : "=&v"(d0),"=&v"(d1),"=&v"(d2),"=&v"(d3)                             \
      : "v"(_b0)); }

#define LD32(AF, BASE)                                                      \
  LD8(AF[0][0],AF[0][1],AF[0][2],AF[0][3],AF[0][4],AF[0][5],AF[0][6],AF[0][7], (BASE));          \
  LD8(AF[1][0],AF[1][1],AF[1][2],AF[1][3],AF[1][4],AF[1][5],AF[1][6],AF[1][7], (BASE)+32768ull); \
  LD8(AF[2][0],AF[2][1],AF[2][2],AF[2][3],AF[2][4],AF[2][5],AF[2][6],AF[2][7], (BASE)+65536ull); \
  LD8(AF[3][0],AF[3][1],AF[3][2],AF[3][3],AF[3][4],AF[3][5],AF[3][6],AF[3][7], (BASE)+98304ull);

#define LD16C4(AF, BASE)                                                    \
  LD4C(AF[0][0],AF[0][1],AF[0][2],AF[0][3], (BASE));                        \
  LD4C(AF[1][0],AF[1][1],AF[1][2],AF[1][3], (BASE)+32768ull);               \
  LD4C(AF[2][0],AF[2][1],AF[2][2],AF[2][3], (BASE)+65536ull);               \
  LD4C(AF[3][0],AF[3][1],AF[3][2],AF[3][3], (BASE)+98304ull);

#define VMWAIT_FENCE                                                        \
  asm volatile("s_waitcnt vmcnt(0)" ::: "memory");                          \
  __builtin_amdgcn_sched_barrier(0)

// ---------------- P1: X fp32 [T][B][1024] -> xfrag bf16 [T][4 mt][32 kc][64 lane][8]
__global__ __launch_bounds__(256) void p1_xfrag(const float* __restrict__ X,
                                                bf16_8* __restrict__ xf) {
  size_t n = (size_t)blockIdx.x * 256 + threadIdx.x;   // 4,194,304 total
  int lane = (int)(n & 63);
  int kc   = (int)((n >> 6) & 31);
  int mt   = (int)((n >> 11) & 3);
  int t    = (int)(n >> 13);
  int b  = 16 * mt + (lane & 15);
  int i0 = 32 * kc + (lane >> 4) * 8;
  const float4* ps = (const float4*)(X + ((size_t)t * 64 + b) * 1024 + i0);
  float4 a = ps[0], c = ps[1];
  bf16_8 v;
  v[0]=(__bf16)a.x; v[1]=(__bf16)a.y; v[2]=(__bf16)a.z; v[3]=(__bf16)a.w;
  v[4]=(__bf16)c.x; v[5]=(__bf16)c.y; v[6]=(__bf16)c.z; v[7]=(__bf16)c.w;
  xf[n] = v;
}

// ---------------- P2: Wi,Wh fp32 -> wfrag bf16 [256 cu][64 kc][64 lane][8]
__global__ __launch_bounds__(256) void p2_wfrag(const float* __restrict__ Wi,
                                                const float* __restrict__ Wh,
                                                bf16_8* __restrict__ wf) {
  size_t n = (size_t)blockIdx.x * 256 + threadIdx.x;   // 1,048,576 total
  int lane = (int)(n & 63);
  int kc   = (int)((n >> 6) & 63);
  int cu   = (int)(n >> 12);
  int n16 = lane & 15;
  int g  = n16 >> 2;
  int jj = n16 & 3;
  int col = 4 * cu + jj;
  int k = 32 * kc + (lane >> 4) * 8;
  const float* src = (k < 1024)
      ? (Wi + ((size_t)g * 1024 + col) * 1024 + k)
      : (Wh + ((size_t)g * 1024 + col) * 1024 + (k - 1024));
  const float4* ps = (const float4*)src;
  float4 a = ps[0], c = ps[1];
  bf16_8 v;
  v[0]=(__bf16)a.x; v[1]=(__bf16)a.y; v[2]=(__bf16)a.z; v[3]=(__bf16)a.w;
  v[4]=(__bf16)c.x; v[5]=(__bf16)c.y; v[6]=(__bf16)c.z; v[7]=(__bf16)c.w;
  wf[n] = v;
}

// ---------------- persistent LSTM: 256 blocks x 512 threads, ONE sync/step.
// DATAFLOW-MATCHED RELEASE: wave wv's h-slice (kc 4wv..4wv+3 = h-cols
// [128wv,128wv+128)) is produced by exactly group wv (CUs 32wv..32wv+31).
// The 32nd arriver of group g writes groupflag[g] directly (no root, no
// fan-out); wave wv gates on groupflag[wv]. Early groups release their
// consumer waves early -> their LLC h-loads overlap the straggler group's
// publish; the block __syncthreads absorbs the spread.
__global__ __launch_bounds__(512, 2) void lstm_persist(
    const float* __restrict__ bi, const float* __restrict__ bh,
    const s16_8* __restrict__ xfrag, const s16_8* __restrict__ wfrag,
    s16_8* __restrict__ hfrag, float* __restrict__ out,
    unsigned int* __restrict__ ctr)
{
  __shared__ float gx[2][4][64][17];    // x-partials, dbuf           34,816 B
  __shared__ float gh[8][64][17];       // h-partials (8 waves)       34,816 B
  __shared__ float hvals[2][4][64];     // h results, dbuf             2,048 B
  __shared__ unsigned cell_done;        // intra-block arrive counter

  const int tid  = threadIdx.x;
  const int cu   = blockIdx.x;
  const int wv   = tid >> 6;
  const int lane = tid & 63;
  const bool ish = (wv >= 4);

  // resident W B-frags: h-slice (4 chunks) all waves; x-slice x-waves only
  s16_8 whf[4];
#pragma unroll
  for (int i = 0; i < 4; ++i)
    whf[i] = wfrag[((size_t)cu * 64 + 32 + wv * 4 + i) * 64 + lane];
#pragma unroll
  for (int i = 0; i < 4; ++i) asm volatile("" : "+v"(whf[i]));
  s16_8 wxf[8];
  if (!ish) {
#pragma unroll
    for (int i = 0; i < 8; ++i)
      wxf[i] = wfrag[((size_t)cu * 64 + wv * 8 + i) * 64 + lane];
#pragma unroll
    for (int i = 0; i < 8; ++i) asm volatile("" : "+v"(wxf[i]));
  }

  // cell identity (threads 256..511): 4 consecutive lanes = 4 cols of 1 batch
  const int et  = tid - 256;
  const int ejj = et & 3;
  const int eb  = et >> 2;
  const int j   = cu * 4 + ejj;
  float bias4[4] = {0.f, 0.f, 0.f, 0.f};
  if (ish) {
#pragma unroll
    for (int g = 0; g < 4; ++g) bias4[g] = bi[g * 1024 + j] + bh[g * 1024 + j];
  }
  float cst = 0.f, hval = 0.f;

  unsigned int* grp = ctr + (cu >> 5) * 64;    // 8 group counters, 256 B apart
  unsigned int* flg = ctr + 1024 + wv * 64;    // THIS WAVE'S producer-group flag

  if (tid == 0) cell_done = 0u;

  // ---- prologue: x-waves compute gx(0)
  if (!ish) {
    s16_8 af[4][8];
    LD32(af, (unsigned long long)(const char*)xfrag
             + (unsigned)(wv * 8192 + lane * 16));
    VMWAIT_FENCE;
    f32_4 acc[4];
#pragma unroll
    for (int mt = 0; mt < 4; ++mt) { f32_4 z = {0.f,0.f,0.f,0.f}; acc[mt] = z; }
#pragma unroll
    for (int i = 0; i < 8; ++i)
#pragma unroll
      for (int mt = 0; mt < 4; ++mt)
        acc[mt] = __builtin_amdgcn_mfma_f32_16x16x32_bf16(af[mt][i], wxf[i], acc[mt], 0, 0, 0);
#pragma unroll
    for (int mt = 0; mt < 4; ++mt)
#pragma unroll
      for (int r = 0; r < 4; ++r)
        gx[0][wv][mt * 16 + (lane >> 4) * 4 + r][lane & 15] = acc[mt][r];
  }
  __syncthreads();

  for (int t = 0; t < T_; ++t) {
    // ---- phase A: gate on OWN producer group, then h-GEMM slice (LLC-direct)
    if (t > 0) {
      if (lane == 0) {
        while (__hip_atomic_load(flg, __ATOMIC_RELAXED, __HIP_MEMORY_SCOPE_AGENT)
               < (unsigned)t) {}
      }
      __builtin_amdgcn_sched_barrier(0);   // h loads may not hoist above gate
    }
    {
      s16_8 af[4][4];
      LD16C4(af, (unsigned long long)((const char*)hfrag + (size_t)(t & 1) * 131072)
                 + (unsigned)(wv * 4096 + lane * 16));
      VMWAIT_FENCE;
      f32_4 acc[4];
#pragma unroll
      for (int mt = 0; mt < 4; ++mt) { f32_4 z = {0.f,0.f,0.f,0.f}; acc[mt] = z; }
#pragma unroll
      for (int i = 0; i < 4; ++i)
#pragma unroll
        for (int mt = 0; mt < 4; ++mt)
          acc[mt] = __builtin_amdgcn_mfma_f32_16x16x32_bf16(af[mt][i], whf[i], acc[mt], 0, 0, 0);
#pragma unroll
      for (int mt = 0; mt < 4; ++mt)
#pragma unroll
        for (int r = 0; r < 4; ++r)
          gh[wv][mt * 16 + (lane >> 4) * 4 + r][lane & 15] = acc[mt][r];
    }
    __syncthreads();                       // THE one block barrier per step

    // ---- B-region (no further block syncs)
    if (ish) {
      // cell update
      const int xb = t & 1;
      float g4[4];
#pragma unroll
      for (int g = 0; g < 4; ++g) {
        float s = bias4[g];
        const int row = g * 4 + ejj;
#pragma unroll
        for (int w = 0; w < 4; ++w) s += gx[xb][w][eb][row];
#pragma unroll
        for (int w = 0; w < 8; ++w) s += gh[w][eb][row];
        g4[g] = s;
      }
      float fg = 1.f / (1.f + __expf(-g4[0]));
      float ig = 1.f / (1.f + __expf(-g4[1]));
      float gg = 1.f - 2.f / (__expf(2.f * g4[2]) + 1.f);   // tanh, inf-safe
      float og = 1.f / (1.f + __expf(-g4[3]));
      cst  = fg * cst + ig * gg;
      hval = og * (1.f - 2.f / (__expf(2.f * cst) + 1.f));
      hvals[t & 1][ejj][eb] = hval;

      if (t + 1 < T_) {
        // shfl-pack 4 cols of this batch -> one 8B agent store per 4 lanes
        int base = lane & ~3;
        float p0 = __shfl(hval, base);
        float p1 = __shfl(hval, base + 1);
        float p2 = __shfl(hval, base + 2);
        float p3 = __shfl(hval, base + 3);
        if ((lane & 3) == 0) {
          unsigned long long pk =
              (unsigned long long)__builtin_bit_cast(unsigned short, (__bf16)p0)
            | ((unsigned long long)__builtin_bit_cast(unsigned short, (__bf16)p1) << 16)
            | ((unsigned long long)__builtin_bit_cast(unsigned short, (__bf16)p2) << 32)
            | ((unsigned long long)__builtin_bit_cast(unsigned short, (__bf16)p3) << 48);
          size_t grpi = ((size_t)(((t + 1) & 1) * 4 + (eb >> 4)) * 32 + (cu >> 3)) * 64
                        + (eb & 15) + 16 * ((cu & 7) >> 1);
          unsigned long long* dst =
              (unsigned long long*)((char*)hfrag + grpi * 16 + (cu & 1) * 8);
          __hip_atomic_store(dst, pk, __ATOMIC_RELAXED, __HIP_MEMORY_SCOPE_AGENT);
        }
        asm volatile("s_waitcnt vmcnt(0)" ::: "memory");   // own publish acked
        if (lane == 0)
          __hip_atomic_fetch_add(&cell_done, 1u, __ATOMIC_RELAXED,
                                 __HIP_MEMORY_SCOPE_WORKGROUP);
        if (wv == 4 && lane == 0) {        // single global arrive per CU
          while (__hip_atomic_load(&cell_done, __ATOMIC_RELAXED,
                                   __HIP_MEMORY_SCOPE_WORKGROUP) < 4u * (unsigned)(t + 1)) {}
          // last arriver of group g releases groupflag[g] directly
          unsigned old = atomicAdd(grp, 1u);
          if (old == 32u * (unsigned)(t + 1) - 1u)
            __hip_atomic_store(ctr + 1024 + (cu >> 5) * 64, (unsigned)(t + 1),
                               __ATOMIC_RELAXED, __HIP_MEMORY_SCOPE_AGENT);
        }
      }
    } else {
      // out(t-1), coalesced float4 (lanes 0-15 per wave, 16 rows each)
      if (t > 0 && lane < 16) {
        const int s = (t - 1) & 1;
        const int row = wv * 16 + lane;
        float4 o4 = make_float4(hvals[s][0][row], hvals[s][1][row],
                                hvals[s][2][row], hvals[s][3][row]);
        *(float4*)(out + ((size_t)(t - 1) * 64 + row) * 1024 + cu * 4) = o4;
      }
      // x-GEMM(t+1) into gx[(t+1)&1] — overlaps cell + release cascade
      if (t + 1 < T_) {
        s16_8 af[4][8];
        LD32(af, (unsigned long long)((const char*)xfrag + (size_t)(t + 1) * 131072)
                 + (unsigned)(wv * 8192 + lane * 16));
        VMWAIT_FENCE;
        f32_4 acc[4];
#pragma unroll
        for (int mt = 0; mt < 4; ++mt) { f32_4 z = {0.f,0.f,0.f,0.f}; acc[mt] = z; }
#pragma unroll
        for (int i = 0; i < 8; ++i)
#pragma unroll
          for (int mt = 0; mt < 4; ++mt)
            acc[mt] = __builtin_amdgcn_mfma_f32_16x16x32_bf16(af[mt][i], wxf[i], acc[mt], 0, 0, 0);
#pragma unroll
        for (int mt = 0; mt < 4; ++mt)
#pragma unroll
          for (int r = 0; r < 4; ++r)
            gx[(t + 1) & 1][wv][mt * 16 + (lane >> 4) * 4 + r][lane & 15] = acc[mt][r];
      }
    }
  }

  __syncthreads();
  // ---- epilogue: out(511) + h_n, c_n
  if (!ish && lane < 16) {
    const int row = wv * 16 + lane;
    float4 o4 = make_float4(hvals[1][0][row], hvals[1][1][row],
                            hvals[1][2][row], hvals[1][3][row]);
    *(float4*)(out + ((size_t)(T_ - 1) * 64 + row) * 1024 + cu * 4) = o4;
  }
  if (ish) {
    out[(size_t)T_ * 65536 + (size_t)eb * 1024 + j] = hval;
    out[(size_t)T_ * 65536 + 65536 + (size_t)eb * 1024 + j] = cst;
  }
}

extern "C" void kernel_launch(void* const* d_in, const int* in_sizes, int n_in,
                              void* d_out, int out_size, void* d_ws, size_t ws_size,
                              hipStream_t stream) {
  (void)in_sizes; (void)n_in;
  const float* X  = (const float*)d_in[0];
  const float* Wi = (const float*)d_in[1];
  const float* Wh = (const float*)d_in[2];
  const float* bi = (const float*)d_in[3];
  const float* bh = (const float*)d_in[4];
  float* out = (float*)d_out;

  char* ws = (char*)d_ws;
  const size_t W_BYTES = (size_t)256 * 64 * 64 * 8 * 2;     // 16,777,216
  const size_t H_BYTES = (size_t)2 * 4 * 32 * 64 * 8 * 2;   //    262,144
  const size_t C_BYTES = 8192;                              // ctrs + group flags
  const size_t X_BYTES = (size_t)512 * 4 * 32 * 64 * 8 * 2; // 67,108,864

  bf16_8* wfrag = (bf16_8*)ws;
  bf16_8* hfrag = (bf16_8*)(ws + W_BYTES);
  unsigned int* ctr = (unsigned int*)(ws + W_BYTES + H_BYTES);

  bf16_8* xfrag;
  if (ws_size >= W_BYTES + H_BYTES + C_BYTES + X_BYTES) {
    xfrag = (bf16_8*)(ws + W_BYTES + H_BYTES + C_BYTES);
  } else {
    // place x-frags in the tail of d_out; out rows clobber xfrag[t'] only for
    // t' < 2t-514 < t+1 (already consumed, skew<=1); final outputs cover all.
    size_t out_bytes = (size_t)out_size * 4;
    xfrag = (bf16_8*)((char*)d_out + out_bytes - X_BYTES);
  }

  hipMemsetAsync(hfrag, 0, 131072, stream);   // zero h buffer 0 (t=0 reads it)
  hipMemsetAsync(ctr, 0, C_BYTES, stream);    // reset counters + group flags

  hipLaunchKernelGGL(p1_xfrag, dim3(16384), dim3(256), 0, stream, X, xfrag);
  hipLaunchKernelGGL(p2_wfrag, dim3(4096), dim3(256), 0, stream, Wi, Wh, wfrag);
  hipLaunchKernelGGL(lstm_persist, dim3(256), dim3(512), 0, stream,
                     bi, bh, (const s16_8*)xfrag, (const s16_8*)wfrag,
                     (s16_8*)hfrag, out, ctr);
}

// Round 19
// 2130.403 us; speedup vs baseline: 1.1734x; 1.0439x over previous
//
#include <hip/hip_runtime.h>
#include <hip/hip_bf16.h>

typedef __bf16  bf16_8 __attribute__((ext_vector_type(8)));
typedef short   s16_8  __attribute__((ext_vector_type(8)));
typedef float   f32_4  __attribute__((ext_vector_type(4)));

#define T_ 512

// Issue 8 global_load_dwordx4 (stride 1024B) from b0 (i=0..3), b0+4096 (4..7).
#define LD8(d0,d1,d2,d3,d4,d5,d6,d7, BASE)                                  \
  { unsigned long long _b0 = (BASE), _b1 = (BASE) + 4096ull;                \
    asm volatile(                                                           \
      "global_load_dwordx4 %0, %8, off\n\t"                                 \
      "global_load_dwordx4 %1, %8, off offset:1024\n\t"                     \
      "global_load_dwordx4 %2, %8, off offset:2048\n\t"                     \
      "global_load_dwordx4 %3, %8, off offset:3072\n\t"                     \
      "global_load_dwordx4 %4, %9, off\n\t"                                 \
      "global_load_dwordx4 %5, %9, off offset:1024\n\t"                     \
      "global_load_dwordx4 %6, %9, off offset:2048\n\t"                     \
      "global_load_dwordx4 %7, %9, off offset:3072\n\t"                     \
      : "=&v"(d0),"=&v"(d1),"=&v"(d2),"=&v"(d3),                            \
        "=&v"(d4),"=&v"(d5),"=&v"(d6),"=&v"(d7)                             \
      : "v"(_b0), "v"(_b1)); }

// Coherent 4-load (4 kc chunks): sc0 sc1 = LLC-direct (r11-proven).
#define LD4C(d0,d1,d2,d3, BASE)                                             \
  { unsigned long long _b0 = (BASE);                                        \
    asm volatile(                                                           \
      "global_load_dwordx4 %0, %4, off sc0 sc1\n\t"                         \
      "global_load_dwordx4 %1, %4, off offset:1024 sc0 sc1\n\t"             \
      "global_load_dwordx4 %2, %4, off offset:2048 sc0 sc1\n\t"             \
      "global_load_dwordx4 %3, %4, off offset:3072 sc0 sc1\n\t"             \
      : "=&v"(d0),"=&v"(d1),"=&v"(d2),"=&v"(d3)                             \
      : "v"(_b0)); }

#define VMWAIT_FENCE                                                        \
  asm volatile("s_waitcnt vmcnt(0)" ::: "memory");                          \
  __builtin_amdgcn_sched_barrier(0)

// ---------------- P1: X fp32 [T][B][1024] -> xfrag bf16 [T][4 mt][32 kc][64 lane][8]
__global__ __launch_bounds__(256) void p1_xfrag(const float* __restrict__ X,
                                                bf16_8* __restrict__ xf) {
  size_t n = (size_t)blockIdx.x * 256 + threadIdx.x;   // 4,194,304 total
  int lane = (int)(n & 63);
  int kc   = (int)((n >> 6) & 31);
  int mt   = (int)((n >> 11) & 3);
  int t    = (int)(n >> 13);
  int b  = 16 * mt + (lane & 15);
  int i0 = 32 * kc + (lane >> 4) * 8;
  const float4* ps = (const float4*)(X + ((size_t)t * 64 + b) * 1024 + i0);
  float4 a = ps[0], c = ps[1];
  bf16_8 v;
  v[0]=(__bf16)a.x; v[1]=(__bf16)a.y; v[2]=(__bf16)a.z; v[3]=(__bf16)a.w;
  v[4]=(__bf16)c.x; v[5]=(__bf16)c.y; v[6]=(__bf16)c.z; v[7]=(__bf16)c.w;
  xf[n] = v;
}

// ---------------- P2 (r14-proven): Wi,Wh fp32 -> wfrag bf16 [128 c][2 nt][64 kc][64 lane][8]
// Col-block c owns hcols 8c..8c+7, 32 W-rows = 4 gates x 8 cols.
// r = nt*16 + (lane&15): g = r>>3, q = r&7; col = 8c+q.
// k = 32*kc + (lane>>4)*8 + e (kc<32: Wi, else Wh).
__global__ __launch_bounds__(256) void p2_wfrag(const float* __restrict__ Wi,
                                                const float* __restrict__ Wh,
                                                bf16_8* __restrict__ wf) {
  size_t n = (size_t)blockIdx.x * 256 + threadIdx.x;   // 1,048,576 total
  int lane = (int)(n & 63);
  int kc   = (int)((n >> 6) & 63);
  int nt   = (int)((n >> 12) & 1);
  int c    = (int)(n >> 13);
  int n16 = lane & 15;
  int g   = 2 * nt + (n16 >> 3);
  int col = c * 8 + (n16 & 7);
  int k = 32 * kc + (lane >> 4) * 8;
  const float* src = (k < 1024)
      ? (Wi + ((size_t)g * 1024 + col) * 1024 + k)
      : (Wh + ((size_t)g * 1024 + col) * 1024 + (k - 1024));
  const float4* ps = (const float4*)src;
  float4 a = ps[0], cc = ps[1];
  bf16_8 v;
  v[0]=(__bf16)a.x; v[1]=(__bf16)a.y; v[2]=(__bf16)a.z; v[3]=(__bf16)a.w;
  v[4]=(__bf16)cc.x; v[5]=(__bf16)cc.y; v[6]=(__bf16)cc.z; v[7]=(__bf16)cc.w;
  wf[n] = v;
}

// ---------------- persistent LSTM: 256 blocks x 512 threads, batch-split.
// Block b: S=b&1 (batch rows 32S..32S+31), c=b>>1 (hcols 8c..8c+7).
// Per-CU h-ingest halves to 64 KB (only own half's rows); x-ingest 64 KB.
// Sync: 16 groups of 16 — group (S,wv) = blocks {(S,c): c in [16wv,16wv+16)}
// produces wave wv's k-slice (cols [128wv,128wv+128)) for half S; last
// arriver writes flag[S*8+wv] (r18 mechanism). Cross-half skew guard <=2
// protects the xfrag-in-dout-tail placement.
__global__ __launch_bounds__(512, 2) void lstm_persist(
    const float* __restrict__ bi, const float* __restrict__ bh,
    const s16_8* __restrict__ xfrag, const s16_8* __restrict__ wfrag,
    s16_8* __restrict__ hfrag, float* __restrict__ out,
    unsigned int* __restrict__ ctr)
{
  __shared__ float gx[2][4][32][33];    // x-partials, dbuf           33,792 B
  __shared__ float gh[8][32][33];       // h-partials (8 waves)       33,792 B
  __shared__ float hvals[2][32][9];     // h results, dbuf             2,304 B
  __shared__ unsigned cell_done;        // intra-block arrive counter

  const int tid  = threadIdx.x;
  const int bid  = blockIdx.x;
  const int S    = bid & 1;             // batch half
  const int c    = bid >> 1;            // col-block (8 cols)
  const int wv   = tid >> 6;
  const int lane = tid & 63;
  const bool ish = (wv >= 4);

  // resident W B-frags: h-slice (2nt x 4kc) all waves; x-slice x-waves only
  s16_8 whf[2][4];
#pragma unroll
  for (int nt = 0; nt < 2; ++nt)
#pragma unroll
    for (int i = 0; i < 4; ++i)
      whf[nt][i] = wfrag[(((size_t)c * 2 + nt) * 64 + 32 + wv * 4 + i) * 64 + lane];
#pragma unroll
  for (int nt = 0; nt < 2; ++nt)
#pragma unroll
    for (int i = 0; i < 4; ++i) asm volatile("" : "+v"(whf[nt][i]));
  s16_8 wxf[2][8];
  if (!ish) {
#pragma unroll
    for (int nt = 0; nt < 2; ++nt)
#pragma unroll
      for (int i = 0; i < 8; ++i)
        wxf[nt][i] = wfrag[(((size_t)c * 2 + nt) * 64 + wv * 8 + i) * 64 + lane];
#pragma unroll
    for (int nt = 0; nt < 2; ++nt)
#pragma unroll
      for (int i = 0; i < 8; ++i) asm volatile("" : "+v"(wxf[nt][i]));
  }

  // cell identity (threads 256..511): q = col-in-block (8), b' = batch-in-half (32)
  const int et = tid - 256;
  const int eq = et & 7;
  const int eb = et >> 3;
  float bias4[4] = {0.f, 0.f, 0.f, 0.f};
  if (ish) {
#pragma unroll
    for (int g = 0; g < 4; ++g)
      bias4[g] = bi[g * 1024 + c * 8 + eq] + bh[g * 1024 + c * 8 + eq];
  }
  float cst = 0.f, hval = 0.f;

  const int gi = S * 8 + (c >> 4);              // this block's producer group
  unsigned int* grp   = ctr + gi * 64;          // 16 group counters, 256B apart
  unsigned int* flg   = ctr + 1024 + (S * 8 + wv) * 64;        // own gate
  unsigned int* oflg  = ctr + 1024 + ((1 - S) * 8 + wv) * 64;  // skew guard

  if (tid == 0) cell_done = 0u;

  // ---- prologue: x-waves compute gx(0) (own half's 2 mt groups)
  if (!ish) {
    s16_8 af[2][8];
    unsigned long long xb0 = (unsigned long long)(const char*)xfrag
        + (unsigned)((2 * S) * 32768 + wv * 8192 + lane * 16);
    LD8(af[0][0],af[0][1],af[0][2],af[0][3],af[0][4],af[0][5],af[0][6],af[0][7], xb0);
    LD8(af[1][0],af[1][1],af[1][2],af[1][3],af[1][4],af[1][5],af[1][6],af[1][7], xb0 + 32768ull);
    VMWAIT_FENCE;
    f32_4 acc[2][2];
#pragma unroll
    for (int m = 0; m < 2; ++m)
#pragma unroll
      for (int nt = 0; nt < 2; ++nt) { f32_4 z = {0.f,0.f,0.f,0.f}; acc[m][nt] = z; }
#pragma unroll
    for (int i = 0; i < 8; ++i)
#pragma unroll
      for (int m = 0; m < 2; ++m)
#pragma unroll
        for (int nt = 0; nt < 2; ++nt)
          acc[m][nt] = __builtin_amdgcn_mfma_f32_16x16x32_bf16(af[m][i], wxf[nt][i], acc[m][nt], 0, 0, 0);
#pragma unroll
    for (int m = 0; m < 2; ++m)
#pragma unroll
      for (int nt = 0; nt < 2; ++nt)
#pragma unroll
        for (int r = 0; r < 4; ++r)
          gx[0][wv][m * 16 + (lane >> 4) * 4 + r][nt * 16 + (lane & 15)] = acc[m][nt][r];
  }
  __syncthreads();

  for (int t = 0; t < T_; ++t) {
    // ---- phase A: gate on own producer group; h-GEMM slice (LLC-direct)
    if (t > 0) {
      if (lane == 0) {
        while (__hip_atomic_load(flg, __ATOMIC_RELAXED, __HIP_MEMORY_SCOPE_AGENT)
               < (unsigned)t) {}
      }
      if (lane == 1 && t > 2) {          // skew guard: halves stay within 2
        while (__hip_atomic_load(oflg, __ATOMIC_RELAXED, __HIP_MEMORY_SCOPE_AGENT)
               < (unsigned)(t - 2)) {}
      }
      __builtin_amdgcn_sched_barrier(0);
    }
    {
      s16_8 af[2][4];
      unsigned long long hb = (unsigned long long)((const char*)hfrag
          + (size_t)(t & 1) * 131072)
          + (unsigned)((2 * S) * 32768 + wv * 4096 + lane * 16);
      LD4C(af[0][0],af[0][1],af[0][2],af[0][3], hb);
      LD4C(af[1][0],af[1][1],af[1][2],af[1][3], hb + 32768ull);
      VMWAIT_FENCE;
      f32_4 acc[2][2];
#pragma unroll
      for (int m = 0; m < 2; ++m)
#pragma unroll
        for (int nt = 0; nt < 2; ++nt) { f32_4 z = {0.f,0.f,0.f,0.f}; acc[m][nt] = z; }
#pragma unroll
      for (int i = 0; i < 4; ++i)
#pragma unroll
        for (int m = 0; m < 2; ++m)
#pragma unroll
          for (int nt = 0; nt < 2; ++nt)
            acc[m][nt] = __builtin_amdgcn_mfma_f32_16x16x32_bf16(af[m][i], whf[nt][i], acc[m][nt], 0, 0, 0);
#pragma unroll
      for (int m = 0; m < 2; ++m)
#pragma unroll
        for (int nt = 0; nt < 2; ++nt)
#pragma unroll
          for (int r = 0; r < 4; ++r)
            gh[wv][m * 16 + (lane >> 4) * 4 + r][nt * 16 + (lane & 15)] = acc[m][nt][r];
    }
    __syncthreads();                       // THE one block barrier per step

    // ---- B-region (no further block syncs)
    if (ish) {
      // cell update: output col 8c+eq, batch row 32S+eb
      const int xb = t & 1;
      float g4[4];
#pragma unroll
      for (int g = 0; g < 4; ++g) {
        const int row = g * 8 + eq;
        float s = bias4[g];
#pragma unroll
        for (int w = 0; w < 4; ++w) s += gx[xb][w][eb][row];
#pragma unroll
        for (int w = 0; w < 8; ++w) s += gh[w][eb][row];
        g4[g] = s;
      }
      float fg = 1.f / (1.f + __expf(-g4[0]));
      float ig = 1.f / (1.f + __expf(-g4[1]));
      float gg = 1.f - 2.f / (__expf(2.f * g4[2]) + 1.f);   // tanh, inf-safe
      float og = 1.f / (1.f + __expf(-g4[3]));
      cst  = fg * cst + ig * gg;
      hval = og * (1.f - 2.f / (__expf(2.f * cst) + 1.f));
      hvals[t & 1][eb][eq] = hval;

      if (t + 1 < T_) {
        // pack 8 cols of one batch (one 16B fragment word) via shfl over 8
        int base = lane & ~7;
        float p0 = __shfl(hval, base),     p1 = __shfl(hval, base + 1);
        float p2 = __shfl(hval, base + 2), p3 = __shfl(hval, base + 3);
        float p4 = __shfl(hval, base + 4), p5 = __shfl(hval, base + 5);
        float p6 = __shfl(hval, base + 6), p7 = __shfl(hval, base + 7);
        if ((lane & 7) == 0) {
          unsigned long long pk0 =
              (unsigned long long)__builtin_bit_cast(unsigned short, (__bf16)p0)
            | ((unsigned long long)__builtin_bit_cast(unsigned short, (__bf16)p1) << 16)
            | ((unsigned long long)__builtin_bit_cast(unsigned short, (__bf16)p2) << 32)
            | ((unsigned long long)__builtin_bit_cast(unsigned short, (__bf16)p3) << 48);
          unsigned long long pk1 =
              (unsigned long long)__builtin_bit_cast(unsigned short, (__bf16)p4)
            | ((unsigned long long)__builtin_bit_cast(unsigned short, (__bf16)p5) << 16)
            | ((unsigned long long)__builtin_bit_cast(unsigned short, (__bf16)p6) << 32)
            | ((unsigned long long)__builtin_bit_cast(unsigned short, (__bf16)p7) << 48);
          const int mt = 2 * S + (eb >> 4);
          size_t b16 = ((size_t)(mt * 32 + (c >> 2)) * 64
                        + (c & 3) * 16 + (eb & 15)) * 16;
          unsigned long long* dst = (unsigned long long*)
              ((char*)hfrag + (size_t)((t + 1) & 1) * 131072 + b16);
          __hip_atomic_store(dst,     pk0, __ATOMIC_RELAXED, __HIP_MEMORY_SCOPE_AGENT);
          __hip_atomic_store(dst + 1, pk1, __ATOMIC_RELAXED, __HIP_MEMORY_SCOPE_AGENT);
        }
        asm volatile("s_waitcnt vmcnt(0)" ::: "memory");   // own publish acked
        if (lane == 0)
          __hip_atomic_fetch_add(&cell_done, 1u, __ATOMIC_RELAXED,
                                 __HIP_MEMORY_SCOPE_WORKGROUP);
        if (wv == 4 && lane == 0) {        // single global arrive per CU
          while (__hip_atomic_load(&cell_done, __ATOMIC_RELAXED,
                                   __HIP_MEMORY_SCOPE_WORKGROUP) < 4u * (unsigned)(t + 1)) {}
          unsigned old = atomicAdd(grp, 1u);
          if (old == 16u * (unsigned)(t + 1) - 1u)   // last of 16 -> release
            __hip_atomic_store(ctr + 1024 + gi * 64, (unsigned)(t + 1),
                               __ATOMIC_RELAXED, __HIP_MEMORY_SCOPE_AGENT);
        }
      }
    } else {
      // out(t-1): 32 rows x 8 cols, float4 x2 per row (16 lanes/wave)
      if (t > 0 && lane < 16) {
        const int s = (t - 1) & 1;
        const int b2 = wv * 8 + (lane >> 1);
        const int q0 = (lane & 1) * 4;
        float4 o4 = make_float4(hvals[s][b2][q0],     hvals[s][b2][q0 + 1],
                                hvals[s][b2][q0 + 2], hvals[s][b2][q0 + 3]);
        *(float4*)(out + ((size_t)(t - 1) * 64 + 32 * S + b2) * 1024 + c * 8 + q0) = o4;
      }
      // x-GEMM(t+1) into gx[(t+1)&1] — overlaps cell + release cascade
      if (t + 1 < T_) {
        s16_8 af[2][8];
        unsigned long long xb0 = (unsigned long long)((const char*)xfrag
            + (size_t)(t + 1) * 131072)
            + (unsigned)((2 * S) * 32768 + wv * 8192 + lane * 16);
        LD8(af[0][0],af[0][1],af[0][2],af[0][3],af[0][4],af[0][5],af[0][6],af[0][7], xb0);
        LD8(af[1][0],af[1][1],af[1][2],af[1][3],af[1][4],af[1][5],af[1][6],af[1][7], xb0 + 32768ull);
        VMWAIT_FENCE;
        f32_4 acc[2][2];
#pragma unroll
        for (int m = 0; m < 2; ++m)
#pragma unroll
          for (int nt = 0; nt < 2; ++nt) { f32_4 z = {0.f,0.f,0.f,0.f}; acc[m][nt] = z; }
#pragma unroll
        for (int i = 0; i < 8; ++i)
#pragma unroll
          for (int m = 0; m < 2; ++m)
#pragma unroll
            for (int nt = 0; nt < 2; ++nt)
              acc[m][nt] = __builtin_amdgcn_mfma_f32_16x16x32_bf16(af[m][i], wxf[nt][i], acc[m][nt], 0, 0, 0);
#pragma unroll
        for (int m = 0; m < 2; ++m)
#pragma unroll
          for (int nt = 0; nt < 2; ++nt)
#pragma unroll
            for (int r = 0; r < 4; ++r)
              gx[(t + 1) & 1][wv][m * 16 + (lane >> 4) * 4 + r][nt * 16 + (lane & 15)] = acc[m][nt][r];
      }
    }
  }

  __syncthreads();
  // ---- epilogue: out(511) + h_n, c_n
  if (!ish && lane < 16) {
    const int b2 = wv * 8 + (lane >> 1);
    const int q0 = (lane & 1) * 4;
    float4 o4 = make_float4(hvals[1][b2][q0],     hvals[1][b2][q0 + 1],
                            hvals[1][b2][q0 + 2], hvals[1][b2][q0 + 3]);
    *(float4*)(out + ((size_t)(T_ - 1) * 64 + 32 * S + b2) * 1024 + c * 8 + q0) = o4;
  }
  if (ish) {
    out[(size_t)T_ * 65536 + (size_t)(32 * S + eb) * 1024 + c * 8 + eq] = hval;
    out[(size_t)T_ * 65536 + 65536 + (size_t)(32 * S + eb) * 1024 + c * 8 + eq] = cst;
  }
}

extern "C" void kernel_launch(void* const* d_in, const int* in_sizes, int n_in,
                              void* d_out, int out_size, void* d_ws, size_t ws_size,
                              hipStream_t stream) {
  (void)in_sizes; (void)n_in;
  const float* X  = (const float*)d_in[0];
  const float* Wi = (const float*)d_in[1];
  const float* Wh = (const float*)d_in[2];
  const float* bi = (const float*)d_in[3];
  const float* bh = (const float*)d_in[4];
  float* out = (float*)d_out;

  char* ws = (char*)d_ws;
  const size_t W_BYTES = (size_t)128 * 2 * 64 * 64 * 8 * 2; // 16,777,216
  const size_t H_BYTES = (size_t)2 * 4 * 32 * 64 * 8 * 2;   //    262,144
  const size_t C_BYTES = 16384;                             // 16 ctrs + 16 flags
  const size_t X_BYTES = (size_t)512 * 4 * 32 * 64 * 8 * 2; // 67,108,864

  bf16_8* wfrag = (bf16_8*)ws;
  bf16_8* hfrag = (bf16_8*)(ws + W_BYTES);
  unsigned int* ctr = (unsigned int*)(ws + W_BYTES + H_BYTES);

  bf16_8* xfrag;
  if (ws_size >= W_BYTES + H_BYTES + C_BYTES + X_BYTES) {
    xfrag = (bf16_8*)(ws + W_BYTES + H_BYTES + C_BYTES);
  } else {
    // tail of d_out; hazard needs cross-half skew >= 8 near t~500 — the
    // gate's skew guard caps it at 2; final outputs cover everything.
    size_t out_bytes = (size_t)out_size * 4;
    xfrag = (bf16_8*)((char*)d_out + out_bytes - X_BYTES);
  }

  hipMemsetAsync(hfrag, 0, 131072, stream);   // zero h slot 0 (t=0 reads it)
  hipMemsetAsync(ctr, 0, C_BYTES, stream);    // reset counters + flags

  hipLaunchKernelGGL(p1_xfrag, dim3(16384), dim3(256), 0, stream, X, xfrag);
  hipLaunchKernelGGL(p2_wfrag, dim3(4096), dim3(256), 0, stream, Wi, Wh, wfrag);
  hipLaunchKernelGGL(lstm_persist, dim3(256), dim3(512), 0, stream,
                     bi, bh, (const s16_8*)xfrag, (const s16_8*)wfrag,
                     (s16_8*)hfrag, out, ctr);
}

// Round 20
// 1920.674 us; speedup vs baseline: 1.3015x; 1.1092x over previous
//
#include <hip/hip_runtime.h>
#include <hip/hip_bf16.h>

typedef __bf16  bf16_8 __attribute__((ext_vector_type(8)));
typedef short   s16_8  __attribute__((ext_vector_type(8)));
typedef float   f32_4  __attribute__((ext_vector_type(4)));

#define T_ 512

// Issue 8 global_load_dwordx4 (stride 1024B) from b0 (i=0..3), b0+4096 (4..7).
#define LD8(d0,d1,d2,d3,d4,d5,d6,d7, BASE)                                  \
  { unsigned long long _b0 = (BASE), _b1 = (BASE) + 4096ull;                \
    asm volatile(                                                           \
      "global_load_dwordx4 %0, %8, off\n\t"                                 \
      "global_load_dwordx4 %1, %8, off offset:1024\n\t"                     \
      "global_load_dwordx4 %2, %8, off offset:2048\n\t"                     \
      "global_load_dwordx4 %3, %8, off offset:3072\n\t"                     \
      "global_load_dwordx4 %4, %9, off\n\t"                                 \
      "global_load_dwordx4 %5, %9, off offset:1024\n\t"                     \
      "global_load_dwordx4 %6, %9, off offset:2048\n\t"                     \
      "global_load_dwordx4 %7, %9, off offset:3072\n\t"                     \
      : "=&v"(d0),"=&v"(d1),"=&v"(d2),"=&v"(d3),                            \
        "=&v"(d4),"=&v"(d5),"=&v"(d6),"=&v"(d7)                             \
      : "v"(_b0), "v"(_b1)); }

// Coherent 4-load (4 kc chunks): sc0 sc1 = LLC-direct (r11-proven).
#define LD4C(d0,d1,d2,d3, BASE)                                             \
  { unsigned long long _b0 = (BASE);                                        \
    asm volatile(                                                           \
      "global_load_dwordx4 %0, %4, off sc0 sc1\n\t"                         \
      "global_load_dwordx4 %1, %4, off offset:1024 sc0 sc1\n\t"             \
      "global_load_dwordx4 %2, %4, off offset:2048 sc0 sc1\n\t"             \
      "global_load_dwordx4 %3, %4, off offset:3072 sc0 sc1\n\t"             \
      : "=&v"(d0),"=&v"(d1),"=&v"(d2),"=&v"(d3)                             \
      : "v"(_b0)); }

#define VMWAIT_FENCE                                                        \
  asm volatile("s_waitcnt vmcnt(0)" ::: "memory");                          \
  __builtin_amdgcn_sched_barrier(0)

// ---------------- P1: X fp32 [T][B][1024] -> xfrag bf16 [T][4 mt][32 kc][64 lane][8]
__global__ __launch_bounds__(256) void p1_xfrag(const float* __restrict__ X,
                                                bf16_8* __restrict__ xf) {
  size_t n = (size_t)blockIdx.x * 256 + threadIdx.x;   // 4,194,304 total
  int lane = (int)(n & 63);
  int kc   = (int)((n >> 6) & 31);
  int mt   = (int)((n >> 11) & 3);
  int t    = (int)(n >> 13);
  int b  = 16 * mt + (lane & 15);
  int i0 = 32 * kc + (lane >> 4) * 8;
  const float4* ps = (const float4*)(X + ((size_t)t * 64 + b) * 1024 + i0);
  float4 a = ps[0], c = ps[1];
  bf16_8 v;
  v[0]=(__bf16)a.x; v[1]=(__bf16)a.y; v[2]=(__bf16)a.z; v[3]=(__bf16)a.w;
  v[4]=(__bf16)c.x; v[5]=(__bf16)c.y; v[6]=(__bf16)c.z; v[7]=(__bf16)c.w;
  xf[n] = v;
}

// ---------------- P2 (r14-proven): Wi,Wh fp32 -> wfrag bf16 [128 c][2 nt][64 kc][64 lane][8]
__global__ __launch_bounds__(256) void p2_wfrag(const float* __restrict__ Wi,
                                                const float* __restrict__ Wh,
                                                bf16_8* __restrict__ wf) {
  size_t n = (size_t)blockIdx.x * 256 + threadIdx.x;   // 1,048,576 total
  int lane = (int)(n & 63);
  int kc   = (int)((n >> 6) & 63);
  int nt   = (int)((n >> 12) & 1);
  int c    = (int)(n >> 13);
  int n16 = lane & 15;
  int g   = 2 * nt + (n16 >> 3);
  int col = c * 8 + (n16 & 7);
  int k = 32 * kc + (lane >> 4) * 8;
  const float* src = (k < 1024)
      ? (Wi + ((size_t)g * 1024 + col) * 1024 + k)
      : (Wh + ((size_t)g * 1024 + col) * 1024 + (k - 1024));
  const float4* ps = (const float4*)src;
  float4 a = ps[0], cc = ps[1];
  bf16_8 v;
  v[0]=(__bf16)a.x; v[1]=(__bf16)a.y; v[2]=(__bf16)a.z; v[3]=(__bf16)a.w;
  v[4]=(__bf16)cc.x; v[5]=(__bf16)cc.y; v[6]=(__bf16)cc.z; v[7]=(__bf16)cc.w;
  wf[n] = v;
}

// ---------------- persistent LSTM: 256 blocks x 512 threads, batch-split.
// r19 structure; this round: LDS conflict fixes only.
// (1) partial arrays stride 33->36: cell-read bank (4eb+8g+eq)%32, <=2-way.
// (2) publish pack via publisher-lane LDS read of hvals (8 reads x 32 lanes)
//     instead of 8-wide shfl (7 ds_bpermute x 256 lanes).
__global__ __launch_bounds__(512, 2) void lstm_persist(
    const float* __restrict__ bi, const float* __restrict__ bh,
    const s16_8* __restrict__ xfrag, const s16_8* __restrict__ wfrag,
    s16_8* __restrict__ hfrag, float* __restrict__ out,
    unsigned int* __restrict__ ctr)
{
  __shared__ float gx[2][4][32][36];    // x-partials, dbuf           36,864 B
  __shared__ float gh[8][32][36];       // h-partials (8 waves)       36,864 B
  __shared__ float hvals[2][32][9];     // h results, dbuf             2,304 B
  __shared__ unsigned cell_done;        // intra-block arrive counter

  const int tid  = threadIdx.x;
  const int bid  = blockIdx.x;
  const int S    = bid & 1;             // batch half
  const int c    = bid >> 1;            // col-block (8 cols)
  const int wv   = tid >> 6;
  const int lane = tid & 63;
  const bool ish = (wv >= 4);

  // resident W B-frags: h-slice (2nt x 4kc) all waves; x-slice x-waves only
  s16_8 whf[2][4];
#pragma unroll
  for (int nt = 0; nt < 2; ++nt)
#pragma unroll
    for (int i = 0; i < 4; ++i)
      whf[nt][i] = wfrag[(((size_t)c * 2 + nt) * 64 + 32 + wv * 4 + i) * 64 + lane];
#pragma unroll
  for (int nt = 0; nt < 2; ++nt)
#pragma unroll
    for (int i = 0; i < 4; ++i) asm volatile("" : "+v"(whf[nt][i]));
  s16_8 wxf[2][8];
  if (!ish) {
#pragma unroll
    for (int nt = 0; nt < 2; ++nt)
#pragma unroll
      for (int i = 0; i < 8; ++i)
        wxf[nt][i] = wfrag[(((size_t)c * 2 + nt) * 64 + wv * 8 + i) * 64 + lane];
#pragma unroll
    for (int nt = 0; nt < 2; ++nt)
#pragma unroll
      for (int i = 0; i < 8; ++i) asm volatile("" : "+v"(wxf[nt][i]));
  }

  // cell identity (threads 256..511): q = col-in-block (8), b' = batch-in-half (32)
  const int et = tid - 256;
  const int eq = et & 7;
  const int eb = et >> 3;
  float bias4[4] = {0.f, 0.f, 0.f, 0.f};
  if (ish) {
#pragma unroll
    for (int g = 0; g < 4; ++g)
      bias4[g] = bi[g * 1024 + c * 8 + eq] + bh[g * 1024 + c * 8 + eq];
  }
  float cst = 0.f, hval = 0.f;

  const int gi = S * 8 + (c >> 4);              // this block's producer group
  unsigned int* grp   = ctr + gi * 64;          // 16 group counters, 256B apart
  unsigned int* flg   = ctr + 1024 + (S * 8 + wv) * 64;        // own gate
  unsigned int* oflg  = ctr + 1024 + ((1 - S) * 8 + wv) * 64;  // skew guard

  if (tid == 0) cell_done = 0u;

  // ---- prologue: x-waves compute gx(0) (own half's 2 mt groups)
  if (!ish) {
    s16_8 af[2][8];
    unsigned long long xb0 = (unsigned long long)(const char*)xfrag
        + (unsigned)((2 * S) * 32768 + wv * 8192 + lane * 16);
    LD8(af[0][0],af[0][1],af[0][2],af[0][3],af[0][4],af[0][5],af[0][6],af[0][7], xb0);
    LD8(af[1][0],af[1][1],af[1][2],af[1][3],af[1][4],af[1][5],af[1][6],af[1][7], xb0 + 32768ull);
    VMWAIT_FENCE;
    f32_4 acc[2][2];
#pragma unroll
    for (int m = 0; m < 2; ++m)
#pragma unroll
      for (int nt = 0; nt < 2; ++nt) { f32_4 z = {0.f,0.f,0.f,0.f}; acc[m][nt] = z; }
#pragma unroll
    for (int i = 0; i < 8; ++i)
#pragma unroll
      for (int m = 0; m < 2; ++m)
#pragma unroll
        for (int nt = 0; nt < 2; ++nt)
          acc[m][nt] = __builtin_amdgcn_mfma_f32_16x16x32_bf16(af[m][i], wxf[nt][i], acc[m][nt], 0, 0, 0);
#pragma unroll
    for (int m = 0; m < 2; ++m)
#pragma unroll
      for (int nt = 0; nt < 2; ++nt)
#pragma unroll
        for (int r = 0; r < 4; ++r)
          gx[0][wv][m * 16 + (lane >> 4) * 4 + r][nt * 16 + (lane & 15)] = acc[m][nt][r];
  }
  __syncthreads();

  for (int t = 0; t < T_; ++t) {
    // ---- phase A: gate on own producer group; h-GEMM slice (LLC-direct)
    if (t > 0) {
      if (lane == 0) {
        while (__hip_atomic_load(flg, __ATOMIC_RELAXED, __HIP_MEMORY_SCOPE_AGENT)
               < (unsigned)t) {}
      }
      if (lane == 1 && t > 2) {          // skew guard: halves stay within 2
        while (__hip_atomic_load(oflg, __ATOMIC_RELAXED, __HIP_MEMORY_SCOPE_AGENT)
               < (unsigned)(t - 2)) {}
      }
      __builtin_amdgcn_sched_barrier(0);
    }
    {
      s16_8 af[2][4];
      unsigned long long hb = (unsigned long long)((const char*)hfrag
          + (size_t)(t & 1) * 131072)
          + (unsigned)((2 * S) * 32768 + wv * 4096 + lane * 16);
      LD4C(af[0][0],af[0][1],af[0][2],af[0][3], hb);
      LD4C(af[1][0],af[1][1],af[1][2],af[1][3], hb + 32768ull);
      VMWAIT_FENCE;
      f32_4 acc[2][2];
#pragma unroll
      for (int m = 0; m < 2; ++m)
#pragma unroll
        for (int nt = 0; nt < 2; ++nt) { f32_4 z = {0.f,0.f,0.f,0.f}; acc[m][nt] = z; }
#pragma unroll
      for (int i = 0; i < 4; ++i)
#pragma unroll
        for (int m = 0; m < 2; ++m)
#pragma unroll
          for (int nt = 0; nt < 2; ++nt)
            acc[m][nt] = __builtin_amdgcn_mfma_f32_16x16x32_bf16(af[m][i], whf[nt][i], acc[m][nt], 0, 0, 0);
#pragma unroll
      for (int m = 0; m < 2; ++m)
#pragma unroll
        for (int nt = 0; nt < 2; ++nt)
#pragma unroll
          for (int r = 0; r < 4; ++r)
            gh[wv][m * 16 + (lane >> 4) * 4 + r][nt * 16 + (lane & 15)] = acc[m][nt][r];
    }
    __syncthreads();                       // THE one block barrier per step

    // ---- B-region (no further block syncs)
    if (ish) {
      // cell update: output col 8c+eq, batch row 32S+eb
      const int xb = t & 1;
      float g4[4];
#pragma unroll
      for (int g = 0; g < 4; ++g) {
        const int row = g * 8 + eq;
        float s = bias4[g];
#pragma unroll
        for (int w = 0; w < 4; ++w) s += gx[xb][w][eb][row];
#pragma unroll
        for (int w = 0; w < 8; ++w) s += gh[w][eb][row];
        g4[g] = s;
      }
      float fg = 1.f / (1.f + __expf(-g4[0]));
      float ig = 1.f / (1.f + __expf(-g4[1]));
      float gg = 1.f - 2.f / (__expf(2.f * g4[2]) + 1.f);   // tanh, inf-safe
      float og = 1.f / (1.f + __expf(-g4[3]));
      cst  = fg * cst + ig * gg;
      hval = og * (1.f - 2.f / (__expf(2.f * cst) + 1.f));
      hvals[t & 1][eb][eq] = hval;

      if (t + 1 < T_) {
        // publisher lane (eq==0) reads its batch's 8 cols back from LDS
        // (same-wave write->read; compiler orders via lgkmcnt on hvals)
        if (eq == 0) {
          float hv[8];
#pragma unroll
          for (int i = 0; i < 8; ++i) hv[i] = hvals[t & 1][eb][i];
          unsigned long long pk0 =
              (unsigned long long)__builtin_bit_cast(unsigned short, (__bf16)hv[0])
            | ((unsigned long long)__builtin_bit_cast(unsigned short, (__bf16)hv[1]) << 16)
            | ((unsigned long long)__builtin_bit_cast(unsigned short, (__bf16)hv[2]) << 32)
            | ((unsigned long long)__builtin_bit_cast(unsigned short, (__bf16)hv[3]) << 48);
          unsigned long long pk1 =
              (unsigned long long)__builtin_bit_cast(unsigned short, (__bf16)hv[4])
            | ((unsigned long long)__builtin_bit_cast(unsigned short, (__bf16)hv[5]) << 16)
            | ((unsigned long long)__builtin_bit_cast(unsigned short, (__bf16)hv[6]) << 32)
            | ((unsigned long long)__builtin_bit_cast(unsigned short, (__bf16)hv[7]) << 48);
          const int mt = 2 * S + (eb >> 4);
          size_t b16 = ((size_t)(mt * 32 + (c >> 2)) * 64
                        + (c & 3) * 16 + (eb & 15)) * 16;
          unsigned long long* dst = (unsigned long long*)
              ((char*)hfrag + (size_t)((t + 1) & 1) * 131072 + b16);
          __hip_atomic_store(dst,     pk0, __ATOMIC_RELAXED, __HIP_MEMORY_SCOPE_AGENT);
          __hip_atomic_store(dst + 1, pk1, __ATOMIC_RELAXED, __HIP_MEMORY_SCOPE_AGENT);
        }
        asm volatile("s_waitcnt vmcnt(0)" ::: "memory");   // own publish acked
        if (lane == 0)
          __hip_atomic_fetch_add(&cell_done, 1u, __ATOMIC_RELAXED,
                                 __HIP_MEMORY_SCOPE_WORKGROUP);
        if (wv == 4 && lane == 0) {        // single global arrive per CU
          while (__hip_atomic_load(&cell_done, __ATOMIC_RELAXED,
                                   __HIP_MEMORY_SCOPE_WORKGROUP) < 4u * (unsigned)(t + 1)) {}
          unsigned old = atomicAdd(grp, 1u);
          if (old == 16u * (unsigned)(t + 1) - 1u)   // last of 16 -> release
            __hip_atomic_store(ctr + 1024 + gi * 64, (unsigned)(t + 1),
                               __ATOMIC_RELAXED, __HIP_MEMORY_SCOPE_AGENT);
        }
      }
    } else {
      // out(t-1): 32 rows x 8 cols, float4 x2 per row (16 lanes/wave)
      if (t > 0 && lane < 16) {
        const int s = (t - 1) & 1;
        const int b2 = wv * 8 + (lane >> 1);
        const int q0 = (lane & 1) * 4;
        float4 o4 = make_float4(hvals[s][b2][q0],     hvals[s][b2][q0 + 1],
                                hvals[s][b2][q0 + 2], hvals[s][b2][q0 + 3]);
        *(float4*)(out + ((size_t)(t - 1) * 64 + 32 * S + b2) * 1024 + c * 8 + q0) = o4;
      }
      // x-GEMM(t+1) into gx[(t+1)&1] — overlaps cell + release cascade
      if (t + 1 < T_) {
        s16_8 af[2][8];
        unsigned long long xb0 = (unsigned long long)((const char*)xfrag
            + (size_t)(t + 1) * 131072)
            + (unsigned)((2 * S) * 32768 + wv * 8192 + lane * 16);
        LD8(af[0][0],af[0][1],af[0][2],af[0][3],af[0][4],af[0][5],af[0][6],af[0][7], xb0);
        LD8(af[1][0],af[1][1],af[1][2],af[1][3],af[1][4],af[1][5],af[1][6],af[1][7], xb0 + 32768ull);
        VMWAIT_FENCE;
        f32_4 acc[2][2];
#pragma unroll
        for (int m = 0; m < 2; ++m)
#pragma unroll
          for (int nt = 0; nt < 2; ++nt) { f32_4 z = {0.f,0.f,0.f,0.f}; acc[m][nt] = z; }
#pragma unroll
        for (int i = 0; i < 8; ++i)
#pragma unroll
          for (int m = 0; m < 2; ++m)
#pragma unroll
            for (int nt = 0; nt < 2; ++nt)
              acc[m][nt] = __builtin_amdgcn_mfma_f32_16x16x32_bf16(af[m][i], wxf[nt][i], acc[m][nt], 0, 0, 0);
#pragma unroll
        for (int m = 0; m < 2; ++m)
#pragma unroll
          for (int nt = 0; nt < 2; ++nt)
#pragma unroll
            for (int r = 0; r < 4; ++r)
              gx[(t + 1) & 1][wv][m * 16 + (lane >> 4) * 4 + r][nt * 16 + (lane & 15)] = acc[m][nt][r];
      }
    }
  }

  __syncthreads();
  // ---- epilogue: out(511) + h_n, c_n
  if (!ish && lane < 16) {
    const int b2 = wv * 8 + (lane >> 1);
    const int q0 = (lane & 1) * 4;
    float4 o4 = make_float4(hvals[1][b2][q0],     hvals[1][b2][q0 + 1],
                            hvals[1][b2][q0 + 2], hvals[1][b2][q0 + 3]);
    *(float4*)(out + ((size_t)(T_ - 1) * 64 + 32 * S + b2) * 1024 + c * 8 + q0) = o4;
  }
  if (ish) {
    out[(size_t)T_ * 65536 + (size_t)(32 * S + eb) * 1024 + c * 8 + eq] = hval;
    out[(size_t)T_ * 65536 + 65536 + (size_t)(32 * S + eb) * 1024 + c * 8 + eq] = cst;
  }
}

extern "C" void kernel_launch(void* const* d_in, const int* in_sizes, int n_in,
                              void* d_out, int out_size, void* d_ws, size_t ws_size,
                              hipStream_t stream) {
  (void)in_sizes; (void)n_in;
  const float* X  = (const float*)d_in[0];
  const float* Wi = (const float*)d_in[1];
  const float* Wh = (const float*)d_in[2];
  const float* bi = (const float*)d_in[3];
  const float* bh = (const float*)d_in[4];
  float* out = (float*)d_out;

  char* ws = (char*)d_ws;
  const size_t W_BYTES = (size_t)128 * 2 * 64 * 64 * 8 * 2; // 16,777,216
  const size_t H_BYTES = (size_t)2 * 4 * 32 * 64 * 8 * 2;   //    262,144
  const size_t C_BYTES = 16384;                             // 16 ctrs + 16 flags
  const size_t X_BYTES = (size_t)512 * 4 * 32 * 64 * 8 * 2; // 67,108,864

  bf16_8* wfrag = (bf16_8*)ws;
  bf16_8* hfrag = (bf16_8*)(ws + W_BYTES);
  unsigned int* ctr = (unsigned int*)(ws + W_BYTES + H_BYTES);

  bf16_8* xfrag;
  if (ws_size >= W_BYTES + H_BYTES + C_BYTES + X_BYTES) {
    xfrag = (bf16_8*)(ws + W_BYTES + H_BYTES + C_BYTES);
  } else {
    // tail of d_out; hazard needs cross-half skew >= 8 near t~500 — the
    // gate's skew guard caps it at 2; final outputs cover everything.
    size_t out_bytes = (size_t)out_size * 4;
    xfrag = (bf16_8*)((char*)d_out + out_bytes - X_BYTES);
  }

  hipMemsetAsync(hfrag, 0, 131072, stream);   // zero h slot 0 (t=0 reads it)
  hipMemsetAsync(ctr, 0, C_BYTES, stream);    // reset counters + flags

  hipLaunchKernelGGL(p1_xfrag, dim3(16384), dim3(256), 0, stream, X, xfrag);
  hipLaunchKernelGGL(p2_wfrag, dim3(4096), dim3(256), 0, stream, Wi, Wh, wfrag);
  hipLaunchKernelGGL(lstm_persist, dim3(256), dim3(512), 0, stream,
                     bi, bh, (const s16_8*)xfrag, (const s16_8*)wfrag,
                     (s16_8*)hfrag, out, ctr);
}